// Round 16
// baseline (1925.677 us; speedup 1.0000x reference)
//
#include <hip/hip_runtime.h>
#include <hip/hip_bf16.h>
#include <math.h>

#define BB 64
#define TT 200
#define DD 256
#define HH 512
#define NCOL 3584  // 7*H
#define NGRP 4     // independent batch groups (16 batches each)
#define NBLK 64    // recurrent blocks: (pair 0..1) x (j0 0..31), 1 wave each

using bf16x8 = __attribute__((ext_vector_type(8))) short;
using f32x4  = __attribute__((ext_vector_type(4))) float;
typedef unsigned long long u64;

// ---- fast device math ----
__device__ __forceinline__ float frcp_(float x) { return __builtin_amdgcn_rcpf(x); }
__device__ __forceinline__ float sigmoidf_(float x) {
    return frcp_(1.0f + __expf(-x));
}
__device__ __forceinline__ float tanhf_(float x) {
    return 1.0f - 2.0f * frcp_(__expf(2.0f * x) + 1.0f);
}
__device__ __forceinline__ float softplusf_(float x) {
    return fmaxf(x, 0.0f) + __logf(1.0f + __expf(-fabsf(x)));
}
__device__ __forceinline__ short f2bf(float f) {
    union { float f; unsigned u; } v; v.f = f;
    unsigned r = v.u + 0x7fff + ((v.u >> 16) & 1);  // RNE
    return (short)(r >> 16);
}
__device__ __forceinline__ float bf2f(short s) {
    union { unsigned u; float f; } v; v.u = ((unsigned)(unsigned short)s) << 16;
    return v.f;
}

// input (B,T,D) fp32 -> Xbf (B*T, D) bf16
__global__ __launch_bounds__(256) void convert_x_kernel(
    const float* __restrict__ in, short* __restrict__ Xbf)
{
    int idx = blockIdx.x * 256 + threadIdx.x;  // < 819200
    float4 v = ((const float4*)in)[idx];
    short4 s;
    s.x = f2bf(v.x); s.y = f2bf(v.y); s.z = f2bf(v.z); s.w = f2bf(v.w);
    ((short4*)Xbf)[idx] = s;
}

// Wx (D, NCOL) fp32 -> WxP packed B-fragments
__global__ __launch_bounds__(256) void pack_wx_kernel(
    const float* __restrict__ Wx, short* __restrict__ WxP)
{
    int idx = blockIdx.x * 256 + threadIdx.x;  // < 917504
    int jj = idx & 7, lane = (idx >> 3) & 63, kt = (idx >> 9) & 7, nt = idx >> 12;
    int k = kt * 32 + ((lane >> 4) << 3) + jj;
    int col = nt * 16 + (lane & 15);
    WxP[idx] = f2bf(Wx[(size_t)k * NCOL + col]);
}

// Wh (H, NCOL) fp32 -> WhP packed A-fragments grouped per (j0, gate)
__global__ __launch_bounds__(256) void pack_wh_kernel(
    const float* __restrict__ Wh, short* __restrict__ WhP)
{
    int idx = blockIdx.x * 256 + threadIdx.x;  // < 1835008
    int jj = idx & 7, lane = (idx >> 3) & 63, kt = (idx >> 9) & 15;
    int gj = idx >> 13;  // j0*7 + g
    int g = gj % 7, j0 = gj / 7;
    int k = kt * 32 + ((lane >> 4) << 3) + jj;
    int col = g * HH + j0 * 16 + (lane & 15);
    WhP[idx] = f2bf(Wh[(size_t)k * NCOL + col]);
}

// GEMM1: Xb[row][col] = bf16( Xbf(row,:) @ Wx(:,col) + bias[col] )
__global__ __launch_bounds__(256) void precompute_kernel(
    const short* __restrict__ Xbf, const short* __restrict__ WxP,
    const float* __restrict__ bias, short* __restrict__ Xb)
{
    const int tid = threadIdx.x;
    const int lane = tid & 63;
    const int w = tid >> 6;
    const int nb = blockIdx.x;   // 0..27
    const int mb = blockIdx.y;   // 0..199

    f32x4 acc[8];
    #pragma unroll
    for (int i = 0; i < 8; ++i) acc[i] = (f32x4){0.f, 0.f, 0.f, 0.f};

    const int rowA = mb * 64 + w * 16 + (lane & 15);
    const short* __restrict__ ha = Xbf + (size_t)rowA * DD + ((lane >> 4) << 3);
    const short* __restrict__ wbase = WxP + ((size_t)(nb * 8) * 512 + lane) * 8;

    #pragma unroll
    for (int kt = 0; kt < 8; ++kt) {
        bf16x8 a = *(const bf16x8*)(ha + kt * 32);
        #pragma unroll
        for (int i = 0; i < 8; ++i) {
            bf16x8 b = *(const bf16x8*)(wbase + i * 4096 + kt * 512);
            acc[i] = __builtin_amdgcn_mfma_f32_16x16x32_bf16(a, b, acc[i], 0, 0, 0);
        }
    }

    const int colL = lane & 15;
    const int rBase = mb * 64 + w * 16 + ((lane >> 4) << 2);
    #pragma unroll
    for (int i = 0; i < 8; ++i) {
        const int col = (nb * 8 + i) * 16 + colL;
        const float bv = bias[col];
        #pragma unroll
        for (int r = 0; r < 4; ++r) {
            Xb[(size_t)(rBase + r) * NCOL + col] = f2bf(acc[i][r] + bv);
        }
    }
}

// ---- recurrent helpers ----
__device__ __forceinline__ void poll32(const unsigned* fl, int lane) {
    while (true) {
        unsigned f = (lane < 32)
            ? __hip_atomic_load(fl + lane, __ATOMIC_RELAXED,
                                __HIP_MEMORY_SCOPE_AGENT)
            : 1u;
        if (__all((int)(f != 0))) break;
        __builtin_amdgcn_s_sleep(1);
    }
}
__device__ __forceinline__ void load_h32(const u64* hp, u64 (&hr)[32]) {
    #pragma unroll
    for (int kt = 0; kt < 16; ++kt) {
        hr[2 * kt]     = __hip_atomic_load(hp + kt * 8, __ATOMIC_RELAXED,
                                           __HIP_MEMORY_SCOPE_AGENT);
        hr[2 * kt + 1] = __hip_atomic_load(hp + kt * 8 + 1, __ATOMIC_RELAXED,
                                           __HIP_MEMORY_SCOPE_AGENT);
    }
}
__device__ __forceinline__ void gemm112(const u64 (&hr)[32],
    const short* wlds, f32x4 (&acc)[7]) {
    #pragma unroll
    for (int kt = 0; kt < 16; ++kt) {
        union { u64 q[2]; bf16x8 v; } u;
        u.q[0] = hr[2 * kt]; u.q[1] = hr[2 * kt + 1];
        const short* wkt = wlds + kt * 512;
        #pragma unroll
        for (int g = 0; g < 7; ++g) {
            bf16x8 a = *(const bf16x8*)(wkt + g * 8192);
            acc[g] = __builtin_amdgcn_mfma_f32_16x16x32_bf16(a, u.v, acc[g], 0, 0, 0);
        }
    }
}
__device__ __forceinline__ void step_math(
    const f32x4 (&acc)[7], const u64 (&xq)[7], float dtn,
    float (&cdecr)[4], float (&cbarr)[4],
    f32x4 &oc, f32x4 &ocb, f32x4 &od, f32x4 &oo, u64 &hq)
{
    hq = 0ull;
    #pragma unroll
    for (int r = 0; r < 4; ++r) {
        const float gi  = acc[0][r] + bf2f((short)(xq[0] >> (16 * r)));
        const float gf  = acc[1][r] + bf2f((short)(xq[1] >> (16 * r)));
        const float gz  = acc[2][r] + bf2f((short)(xq[2] >> (16 * r)));
        const float go  = acc[3][r] + bf2f((short)(xq[3] >> (16 * r)));
        const float gib = acc[4][r] + bf2f((short)(xq[4] >> (16 * r)));
        const float gfb = acc[5][r] + bf2f((short)(xq[5] >> (16 * r)));
        const float gd  = acc[6][r] + bf2f((short)(xq[6] >> (16 * r)));

        const float i_  = sigmoidf_(gi);
        const float f_  = sigmoidf_(gf);
        const float z_  = tanhf_(gz);
        const float o_  = sigmoidf_(go);
        const float ib_ = sigmoidf_(gib);
        const float fb_ = sigmoidf_(gfb);
        const float d_  = softplusf_(gd);

        const float c_new  = f_ * cdecr[r] + i_ * z_;
        const float cb_new = fb_ * cbarr[r] + ib_ * z_;

        oc[r] = c_new; ocb[r] = cb_new; od[r] = d_; oo[r] = o_;

        const float cdn = cb_new + (c_new - cb_new) * __expf(-d_ * dtn);
        const float hn = o_ * tanhf_(cdn);
        cdecr[r] = cdn;
        cbarr[r] = cb_new;
        hq |= ((u64)(unsigned short)f2bf(hn)) << (16 * r);
    }
}

// Persistent recurrent kernel: 64 single-wave blocks = 2 pairs-of-groups
// x 32 j0-blocks. Block (pair, j0) runs group A=2*pair and B=2*pair+1 in
// alternating phases, sharing ONE Wh LDS slice (same j0). The phase
// interleave removes the ack leg: A's h-store ack is subsumed by phase
// B's h-load vmcnt(0) (in-order retirement), after which A's flag is
// stored -- and vice versa across the step boundary. Two group-steps per
// block period; sync legs overlap the other group's compute.
__global__ __launch_bounds__(64, 1) void recurrent_kernel(
    const short* __restrict__ Xb,    // (B*T, NCOL) bf16
    const short* __restrict__ WhP,   // packed A-frags
    const float* __restrict__ dur,   // (B, T)
    u64* __restrict__ h0,            // (B, H) bf16, u64 view
    u64* __restrict__ h1,
    unsigned* __restrict__ flags,    // [TT][NGRP][8 reps][32 blocks]
    float* __restrict__ out)         // (4, B, T, H)
{
    __shared__ short whL[7 * 16 * 64 * 8];  // 114688 B

    const int lane = threadIdx.x;           // single wave
    const int pair = blockIdx.x >> 5;       // 0..1
    const int j0 = blockIdx.x & 31;         // hcol tile

    // ---- stage Wh block slice into LDS (once; serves BOTH groups) ----
    {
        const bf16x8* __restrict__ src = (const bf16x8*)(WhP + (size_t)j0 * 57344);
        bf16x8* dst = (bf16x8*)whL;
        #pragma unroll
        for (int i = 0; i < 112; ++i) dst[i * 64 + lane] = src[i * 64 + lane];
    }
    __syncthreads();

    const int colL = lane & 15;
    const int gA = pair * 2, gB = pair * 2 + 1;
    const int bA = gA * 16 + colL;
    const int bB = gB * 16 + colL;
    const int hcolBase = j0 * 16 + ((lane >> 4) << 2);
    const int kOff = (lane >> 4) << 3;
    const size_t hB64A = ((size_t)bA * HH + kOff) >> 2;
    const size_t hB64B = ((size_t)bB * HH + kOff) >> 2;
    const short* __restrict__ wlds = whL + lane * 8;
    const int myrep = j0 & 7;
    const size_t S = (size_t)BB * TT * HH;

    float cdecA[4] = {0.f, 0.f, 0.f, 0.f}, cbarA[4] = {0.f, 0.f, 0.f, 0.f};
    float cdecB[4] = {0.f, 0.f, 0.f, 0.f}, cbarB[4] = {0.f, 0.f, 0.f, 0.f};

    // deferred out-store registers
    f32x4 dA_oc, dA_ocb, dA_od, dA_oo;  size_t dA_ob = 0;  // A(t): stored in phase B of t
    f32x4 dB_oc, dB_ocb, dB_od, dB_oo;  size_t dB_ob = 0;  // B(t): stored in phase A of t+1

    // ---- prefetch t=0 gate rows + dt for both groups ----
    u64 xqA[7], xqB[7];
    {
        const u64* xa = (const u64*)(Xb + (size_t)bA * TT * NCOL + hcolBase);
        const u64* xb = (const u64*)(Xb + (size_t)bB * TT * NCOL + hcolBase);
        #pragma unroll
        for (int g = 0; g < 7; ++g) { xqA[g] = xa[g * (HH / 4)]; xqB[g] = xb[g * (HH / 4)]; }
    }
    float dtnA = dur[bA * TT + 1];
    float dtnB = dur[bB * TT + 1];

    #pragma unroll 1
    for (int t = 0; t < TT; ++t) {
        u64 hr[32];
        f32x4 acc[7];

        // ================= Phase A =================
        if (t > 0) {
            poll32(flags + (((size_t)(t - 1) * NGRP + gA) * 8 + myrep) * 32, lane);
            load_h32(((t & 1) ? h1 : h0) + hB64A, hr);
            asm volatile("s_waitcnt vmcnt(0)" ::: "memory");  // hA ready; B.hstore(t-1) acked
            __builtin_amdgcn_sched_barrier(0);
            if (lane < 8) {  // announce B's h_t (stored last phase)
                __hip_atomic_store(
                    &flags[(((size_t)(t - 1) * NGRP + gB) * 8 + lane) * 32 + j0], 1u,
                    __ATOMIC_RELAXED, __HIP_MEMORY_SCOPE_AGENT);
            }
            // deferred outs of B(t-1): retire under GEMM A + poll B
            *(f32x4*)(out + dB_ob)         = dB_oc;
            *(f32x4*)(out + dB_ob + S)     = dB_ocb;
            *(f32x4*)(out + dB_ob + 2 * S) = dB_od;
            *(f32x4*)(out + dB_ob + 3 * S) = dB_oo;
        } else {
            #pragma unroll
            for (int i = 0; i < 32; ++i) hr[i] = 0ull;
        }

        // prefetch A(t+1)
        u64 xqnA[7]; float dtnnA;
        {
            const int tn = (t + 1 < TT) ? t + 1 : t;
            const u64* xa = (const u64*)(Xb + ((size_t)bA * TT + tn) * NCOL + hcolBase);
            #pragma unroll
            for (int g = 0; g < 7; ++g) xqnA[g] = xa[g * (HH / 4)];
            const int tn1 = (tn + 1 < TT) ? tn + 1 : TT - 1;
            dtnnA = dur[bA * TT + tn1];
        }

        #pragma unroll
        for (int g = 0; g < 7; ++g) acc[g] = (f32x4){0.f, 0.f, 0.f, 0.f};
        gemm112(hr, wlds, acc);

        u64 hqA;
        step_math(acc, xqA, dtnA, cdecA, cbarA, dA_oc, dA_ocb, dA_od, dA_oo, hqA);
        dA_ob = ((size_t)bA * TT + t) * HH + hcolBase;

        if (t + 1 < TT) {
            u64* hout = (t & 1) ? h0 : h1;
            __hip_atomic_store(&hout[((size_t)bA * HH + hcolBase) >> 2], hqA,
                               __ATOMIC_RELAXED, __HIP_MEMORY_SCOPE_AGENT);
        }
        #pragma unroll
        for (int g = 0; g < 7; ++g) xqA[g] = xqnA[g];
        dtnA = dtnnA;

        // ================= Phase B =================
        if (t > 0) {
            poll32(flags + (((size_t)(t - 1) * NGRP + gB) * 8 + myrep) * 32, lane);
            load_h32(((t & 1) ? h1 : h0) + hB64B, hr);
        } else {
            #pragma unroll
            for (int i = 0; i < 32; ++i) hr[i] = 0ull;
        }
        asm volatile("s_waitcnt vmcnt(0)" ::: "memory");  // hB ready; A.hstore(t) acked
        __builtin_amdgcn_sched_barrier(0);
        if (t + 1 < TT && lane < 8) {  // announce A's h_{t+1}
            __hip_atomic_store(
                &flags[(((size_t)t * NGRP + gA) * 8 + lane) * 32 + j0], 1u,
                __ATOMIC_RELAXED, __HIP_MEMORY_SCOPE_AGENT);
        }
        // outs of A(t): retire under GEMM B + next poll A
        *(f32x4*)(out + dA_ob)         = dA_oc;
        *(f32x4*)(out + dA_ob + S)     = dA_ocb;
        *(f32x4*)(out + dA_ob + 2 * S) = dA_od;
        *(f32x4*)(out + dA_ob + 3 * S) = dA_oo;

        // prefetch B(t+1)
        u64 xqnB[7]; float dtnnB;
        {
            const int tn = (t + 1 < TT) ? t + 1 : t;
            const u64* xb = (const u64*)(Xb + ((size_t)bB * TT + tn) * NCOL + hcolBase);
            #pragma unroll
            for (int g = 0; g < 7; ++g) xqnB[g] = xb[g * (HH / 4)];
            const int tn1 = (tn + 1 < TT) ? tn + 1 : TT - 1;
            dtnnB = dur[bB * TT + tn1];
        }

        #pragma unroll
        for (int g = 0; g < 7; ++g) acc[g] = (f32x4){0.f, 0.f, 0.f, 0.f};
        gemm112(hr, wlds, acc);

        u64 hqB;
        step_math(acc, xqB, dtnB, cdecB, cbarB, dB_oc, dB_ocb, dB_od, dB_oo, hqB);
        dB_ob = ((size_t)bB * TT + t) * HH + hcolBase;

        if (t + 1 < TT) {
            u64* hout = (t & 1) ? h0 : h1;
            __hip_atomic_store(&hout[((size_t)bB * HH + hcolBase) >> 2], hqB,
                               __ATOMIC_RELAXED, __HIP_MEMORY_SCOPE_AGENT);
        }
        #pragma unroll
        for (int g = 0; g < 7; ++g) xqB[g] = xqnB[g];
        dtnB = dtnnB;
    }

    // ---- final flush: B(TT-1) outs (A(TT-1) stored in its phase B) ----
    *(f32x4*)(out + dB_ob)         = dB_oc;
    *(f32x4*)(out + dB_ob + S)     = dB_ocb;
    *(f32x4*)(out + dB_ob + 2 * S) = dB_od;
    *(f32x4*)(out + dB_ob + 3 * S) = dB_oo;
}

extern "C" void kernel_launch(void* const* d_in, const int* in_sizes, int n_in,
                              void* d_out, int out_size, void* d_ws, size_t ws_size,
                              hipStream_t stream) {
    const float* input = (const float*)d_in[0];  // (B, T, D)
    const float* dur   = (const float*)d_in[1];  // (B, T)
    const float* Wx    = (const float*)d_in[2];  // (D, 7H)
    const float* Wh    = (const float*)d_in[3];  // (H, 7H)
    const float* bias  = (const float*)d_in[4];  // (7H,)
    float* out = (float*)d_out;                  // (4, B, T, H)

    short* Xb  = (short*)d_ws;                       // 45,875,200 shorts
    short* Xbf = Xb + (size_t)TT * BB * NCOL;        // 3,276,800
    short* WxP = Xbf + (size_t)BB * TT * DD;         // 917,504
    short* WhP = WxP + 224 * 8 * 64 * 8;             // 1,835,008
    short* h0s = WhP + 32 * 7 * 16 * 64 * 8;         // 32,768
    short* h1s = h0s + BB * HH;                      // 32,768
    unsigned* flags = (unsigned*)(h1s + BB * HH);    // TT*NGRP*8*32 u32

    // flags must start zeroed every launch (h bufs never read before write)
    hipMemsetAsync(flags, 0, (size_t)TT * NGRP * 8 * 32 * sizeof(unsigned), stream);

    convert_x_kernel<<<3200, 256, 0, stream>>>(input, Xbf);
    pack_wx_kernel<<<3584, 256, 0, stream>>>(Wx, WxP);
    pack_wh_kernel<<<7168, 256, 0, stream>>>(Wh, WhP);

    precompute_kernel<<<dim3(28, 200), 256, 0, stream>>>(Xbf, WxP, bias, Xb);

    recurrent_kernel<<<NBLK, 64, 0, stream>>>(
        Xb, WhP, dur,
        (u64*)h0s, (u64*)h1s,
        flags, out);
}

// Round 17
// 835.432 us; speedup vs baseline: 2.3050x; 2.3050x over previous
//
#include <hip/hip_runtime.h>
#include <hip/hip_bf16.h>
#include <math.h>

#define BB 64
#define TT 200
#define DD 256
#define HH 512
#define NCOL 3584  // 7*H
#define NGRP 4     // independent batch groups (16 batches each)
#define NBLK (NGRP * 32)  // recurrent blocks, 1 wave each

using bf16x8 = __attribute__((ext_vector_type(8))) short;
using f32x4  = __attribute__((ext_vector_type(4))) float;
typedef unsigned long long u64;

// ---- fast device math ----
__device__ __forceinline__ float frcp_(float x) { return __builtin_amdgcn_rcpf(x); }
__device__ __forceinline__ float sigmoidf_(float x) {
    return frcp_(1.0f + __expf(-x));
}
__device__ __forceinline__ float tanhf_(float x) {
    return 1.0f - 2.0f * frcp_(__expf(2.0f * x) + 1.0f);
}
__device__ __forceinline__ float softplusf_(float x) {
    return fmaxf(x, 0.0f) + __logf(1.0f + __expf(-fabsf(x)));
}
__device__ __forceinline__ short f2bf(float f) {
    union { float f; unsigned u; } v; v.f = f;
    unsigned r = v.u + 0x7fff + ((v.u >> 16) & 1);  // RNE
    return (short)(r >> 16);
}
__device__ __forceinline__ float bf2f(short s) {
    union { unsigned u; float f; } v; v.u = ((unsigned)(unsigned short)s) << 16;
    return v.f;
}

// input (B,T,D) fp32 -> Xbf (B*T, D) bf16
__global__ __launch_bounds__(256) void convert_x_kernel(
    const float* __restrict__ in, short* __restrict__ Xbf)
{
    int idx = blockIdx.x * 256 + threadIdx.x;  // < 819200
    float4 v = ((const float4*)in)[idx];
    short4 s;
    s.x = f2bf(v.x); s.y = f2bf(v.y); s.z = f2bf(v.z); s.w = f2bf(v.w);
    ((short4*)Xbf)[idx] = s;
}

// Wx (D, NCOL) fp32 -> WxP packed B-fragments
__global__ __launch_bounds__(256) void pack_wx_kernel(
    const float* __restrict__ Wx, short* __restrict__ WxP)
{
    int idx = blockIdx.x * 256 + threadIdx.x;  // < 917504
    int jj = idx & 7, lane = (idx >> 3) & 63, kt = (idx >> 9) & 7, nt = idx >> 12;
    int k = kt * 32 + ((lane >> 4) << 3) + jj;
    int col = nt * 16 + (lane & 15);
    WxP[idx] = f2bf(Wx[(size_t)k * NCOL + col]);
}

// Wh (H, NCOL) fp32 -> WhP packed A-fragments grouped per (j0, gate)
__global__ __launch_bounds__(256) void pack_wh_kernel(
    const float* __restrict__ Wh, short* __restrict__ WhP)
{
    int idx = blockIdx.x * 256 + threadIdx.x;  // < 1835008
    int jj = idx & 7, lane = (idx >> 3) & 63, kt = (idx >> 9) & 15;
    int gj = idx >> 13;  // j0*7 + g
    int g = gj % 7, j0 = gj / 7;
    int k = kt * 32 + ((lane >> 4) << 3) + jj;
    int col = g * HH + j0 * 16 + (lane & 15);
    WhP[idx] = f2bf(Wh[(size_t)k * NCOL + col]);
}

// GEMM1: Xb[row][col] = bf16( Xbf(row,:) @ Wx(:,col) + bias[col] )
// Widened: each block does 64 rows x 128 cols (8 acc frags/wave, 2x ILP).
__global__ __launch_bounds__(256) void precompute_kernel(
    const short* __restrict__ Xbf, const short* __restrict__ WxP,
    const float* __restrict__ bias, short* __restrict__ Xb)
{
    const int tid = threadIdx.x;
    const int lane = tid & 63;
    const int w = tid >> 6;
    const int nb = blockIdx.x;   // 0..27
    const int mb = blockIdx.y;   // 0..199

    f32x4 acc[8];
    #pragma unroll
    for (int i = 0; i < 8; ++i) acc[i] = (f32x4){0.f, 0.f, 0.f, 0.f};

    const int rowA = mb * 64 + w * 16 + (lane & 15);
    const short* __restrict__ ha = Xbf + (size_t)rowA * DD + ((lane >> 4) << 3);
    const short* __restrict__ wbase = WxP + ((size_t)(nb * 8) * 512 + lane) * 8;

    #pragma unroll
    for (int kt = 0; kt < 8; ++kt) {
        bf16x8 a = *(const bf16x8*)(ha + kt * 32);
        #pragma unroll
        for (int i = 0; i < 8; ++i) {
            bf16x8 b = *(const bf16x8*)(wbase + i * 4096 + kt * 512);
            acc[i] = __builtin_amdgcn_mfma_f32_16x16x32_bf16(a, b, acc[i], 0, 0, 0);
        }
    }

    const int colL = lane & 15;
    const int rBase = mb * 64 + w * 16 + ((lane >> 4) << 2);
    #pragma unroll
    for (int i = 0; i < 8; ++i) {
        const int col = (nb * 8 + i) * 16 + colL;
        const float bv = bias[col];
        #pragma unroll
        for (int r = 0; r < 4; ++r) {
            Xb[(size_t)(rBase + r) * NCOL + col] = f2bf(acc[i][r] + bv);
        }
    }
}

// Persistent recurrent kernel: 128 single-wave blocks = 4 independent
// groups x 32 blocks (R14 structure, protocol verbatim). QUEUE DISCIPLINE
// (the one change vs R14): deferred out-stores of t-1 and the Xb/dur
// prefetch for t+1 are issued right AFTER the h-load burst -- they retire
// under the GEMM+epilogue window, so the publish vmcnt(0) waits only on
// the h store and every poll meets a clean VMEM queue.
__global__ __launch_bounds__(64, 1) void recurrent_kernel(
    const short* __restrict__ Xb,           // (B*T, NCOL) bf16
    const short* __restrict__ WhP,          // packed A-frags
    const float* __restrict__ dur,          // (B, T)
    u64* __restrict__ h0,                   // (B, H) bf16, u64 view
    u64* __restrict__ h1,
    unsigned* __restrict__ flags,           // [TT][NGRP][8 reps][32 blocks]
    float* __restrict__ out)                // (4, B, T, H)
{
    __shared__ short whL[7 * 16 * 64 * 8];  // 114688 B

    const int lane = threadIdx.x;           // single wave
    const int grp = blockIdx.x >> 5;        // 0..3
    const int j0 = blockIdx.x & 31;         // hcol tile

    // ---- stage Wh block slice into LDS (one time) ----
    {
        const bf16x8* __restrict__ src = (const bf16x8*)(WhP + (size_t)j0 * 57344);
        bf16x8* dst = (bf16x8*)whL;
        #pragma unroll
        for (int i = 0; i < 112; ++i) dst[i * 64 + lane] = src[i * 64 + lane];
    }
    __syncthreads();

    const int colL = lane & 15;
    const int b = grp * 16 + colL;                    // fixed batch per lane
    const int hcolBase = j0 * 16 + ((lane >> 4) << 2);
    const int kOff = (lane >> 4) << 3;                // 0,8,16,24
    const size_t hB64base = ((size_t)b * HH + kOff) >> 2;  // u64 index
    const short* __restrict__ wlds = whL + lane * 8;  // + g*8192 + kt*512
    const int myrep = j0 & 7;

    float cdecr[4] = {0.f, 0.f, 0.f, 0.f};
    float cbarr[4] = {0.f, 0.f, 0.f, 0.f};
    const size_t S = (size_t)BB * TT * HH;

    // deferred out-store registers (step t-1's outputs)
    f32x4 d_oc, d_ocb, d_od, d_oo;
    size_t d_ob = 0;

    // ---- prefetch t=0 gate row + dt ----
    u64 xq[7];
    {
        const u64* xb64 = (const u64*)(Xb + (size_t)b * TT * NCOL + hcolBase);
        #pragma unroll
        for (int g = 0; g < 7; ++g) xq[g] = xb64[g * (HH / 4)];
    }
    float dtn = dur[b * TT + 1];

    #pragma unroll 1
    for (int t = 0; t < TT; ++t) {
        // ---- 1. acquire h_t: poll group's per-block flags, then h burst ----
        u64 hr[32];
        if (t > 0) {
            const unsigned* fl =
                flags + (((size_t)(t - 1) * NGRP + grp) * 8 + myrep) * 32;
            while (true) {
                unsigned f = (lane < 32)
                    ? __hip_atomic_load(fl + lane, __ATOMIC_RELAXED,
                                        __HIP_MEMORY_SCOPE_AGENT)
                    : 1u;
                if (__all((int)(f != 0))) break;
                __builtin_amdgcn_s_sleep(1);
            }
            const u64* hin = ((t & 1) ? h1 : h0) + hB64base;
            #pragma unroll
            for (int kt = 0; kt < 16; ++kt) {
                hr[2 * kt]     = __hip_atomic_load(hin + kt * 8,
                                    __ATOMIC_RELAXED, __HIP_MEMORY_SCOPE_AGENT);
                hr[2 * kt + 1] = __hip_atomic_load(hin + kt * 8 + 1,
                                    __ATOMIC_RELAXED, __HIP_MEMORY_SCOPE_AGENT);
            }
        } else {
            #pragma unroll
            for (int i = 0; i < 32; ++i) hr[i] = 0ull;
        }

        // ---- 2. deferred outs of t-1 + prefetch t+1, issued AFTER the
        //         h-loads (h is oldest in queue -> counted waits for GEMM;
        //         these retire under GEMM/epilogue, off the publish drain
        //         and off the next poll) ----
        if (t > 0) {
            *(f32x4*)(out + d_ob)         = d_oc;
            *(f32x4*)(out + d_ob + S)     = d_ocb;
            *(f32x4*)(out + d_ob + 2 * S) = d_od;
            *(f32x4*)(out + d_ob + 3 * S) = d_oo;
        }
        u64 xqn[7];
        float dtnn;
        {
            const int tn = (t + 1 < TT) ? t + 1 : t;
            const u64* xb64n = (const u64*)(Xb + ((size_t)b * TT + tn) * NCOL + hcolBase);
            #pragma unroll
            for (int g = 0; g < 7; ++g) xqn[g] = xb64n[g * (HH / 4)];
            const int tn1 = (tn + 1 < TT) ? tn + 1 : TT - 1;
            dtnn = dur[b * TT + tn1];
        }

        // ---- 3. GEMM: 112 MFMAs, A from LDS, B from hr regs ----
        f32x4 acc[7];
        #pragma unroll
        for (int g = 0; g < 7; ++g) acc[g] = (f32x4){0.f, 0.f, 0.f, 0.f};

        #pragma unroll
        for (int kt = 0; kt < 16; ++kt) {
            union { u64 q[2]; bf16x8 v; } u;
            u.q[0] = hr[2 * kt]; u.q[1] = hr[2 * kt + 1];
            const short* wkt = wlds + kt * 512;
            #pragma unroll
            for (int g = 0; g < 7; ++g) {
                bf16x8 a = *(const bf16x8*)(wkt + g * 8192);
                acc[g] = __builtin_amdgcn_mfma_f32_16x16x32_bf16(a, u.v, acc[g], 0, 0, 0);
            }
        }

        // ---- 4. epilogue (per lane: batch b, hcols hcolBase..+3) ----
        f32x4 oc, ocb, od, oo;
        u64 hq = 0ull;
        #pragma unroll
        for (int r = 0; r < 4; ++r) {
            const float gi  = acc[0][r] + bf2f((short)(xq[0] >> (16 * r)));
            const float gf  = acc[1][r] + bf2f((short)(xq[1] >> (16 * r)));
            const float gz  = acc[2][r] + bf2f((short)(xq[2] >> (16 * r)));
            const float go  = acc[3][r] + bf2f((short)(xq[3] >> (16 * r)));
            const float gib = acc[4][r] + bf2f((short)(xq[4] >> (16 * r)));
            const float gfb = acc[5][r] + bf2f((short)(xq[5] >> (16 * r)));
            const float gd  = acc[6][r] + bf2f((short)(xq[6] >> (16 * r)));

            const float i_  = sigmoidf_(gi);
            const float f_  = sigmoidf_(gf);
            const float z_  = tanhf_(gz);
            const float o_  = sigmoidf_(go);
            const float ib_ = sigmoidf_(gib);
            const float fb_ = sigmoidf_(gfb);
            const float d_  = softplusf_(gd);

            const float c_new  = f_ * cdecr[r] + i_ * z_;
            const float cb_new = fb_ * cbarr[r] + ib_ * z_;

            oc[r] = c_new; ocb[r] = cb_new; od[r] = d_; oo[r] = o_;

            const float cdn = cb_new + (c_new - cb_new) * __expf(-d_ * dtn);
            const float hn = o_ * tanhf_(cdn);
            cdecr[r] = cdn;
            cbarr[r] = cb_new;
            hq |= ((u64)(unsigned short)f2bf(hn)) << (16 * r);
        }

        // ---- 5. publish h_{t+1}: store; vmcnt(0) now waits (almost) only
        //         on the h store; then ONE block flag into 8 replicas ----
        if (t + 1 < TT) {
            u64* hout = (t & 1) ? h0 : h1;
            __hip_atomic_store(&hout[((size_t)b * HH + hcolBase) >> 2], hq,
                               __ATOMIC_RELAXED, __HIP_MEMORY_SCOPE_AGENT);
            asm volatile("s_waitcnt vmcnt(0)" ::: "memory");
            if (lane < 8) {
                __hip_atomic_store(
                    &flags[(((size_t)t * NGRP + grp) * 8 + lane) * 32 + j0], 1u,
                    __ATOMIC_RELAXED, __HIP_MEMORY_SCOPE_AGENT);
            }
        }

        // ---- 6. roll state (registers only; no VMEM until next poll) ----
        d_oc = oc; d_ocb = ocb; d_od = od; d_oo = oo;
        d_ob = ((size_t)b * TT + t) * HH + hcolBase;
        #pragma unroll
        for (int g = 0; g < 7; ++g) xq[g] = xqn[g];
        dtn = dtnn;
    }

    // ---- final flush (t = TT-1 outputs) ----
    *(f32x4*)(out + d_ob)         = d_oc;
    *(f32x4*)(out + d_ob + S)     = d_ocb;
    *(f32x4*)(out + d_ob + 2 * S) = d_od;
    *(f32x4*)(out + d_ob + 3 * S) = d_oo;
}

extern "C" void kernel_launch(void* const* d_in, const int* in_sizes, int n_in,
                              void* d_out, int out_size, void* d_ws, size_t ws_size,
                              hipStream_t stream) {
    const float* input = (const float*)d_in[0];  // (B, T, D)
    const float* dur   = (const float*)d_in[1];  // (B, T)
    const float* Wx    = (const float*)d_in[2];  // (D, 7H)
    const float* Wh    = (const float*)d_in[3];  // (H, 7H)
    const float* bias  = (const float*)d_in[4];  // (7H,)
    float* out = (float*)d_out;                  // (4, B, T, H)

    short* Xb  = (short*)d_ws;                       // 45,875,200 shorts
    short* Xbf = Xb + (size_t)TT * BB * NCOL;        // 3,276,800
    short* WxP = Xbf + (size_t)BB * TT * DD;         // 917,504
    short* WhP = WxP + 224 * 8 * 64 * 8;             // 1,835,008
    short* h0s = WhP + 32 * 7 * 16 * 64 * 8;         // 32,768
    short* h1s = h0s + BB * HH;                      // 32,768
    unsigned* flags = (unsigned*)(h1s + BB * HH);    // TT*NGRP*8*32 u32

    // flags must start zeroed every launch (h bufs never read before write)
    hipMemsetAsync(flags, 0, (size_t)TT * NGRP * 8 * 32 * sizeof(unsigned), stream);

    convert_x_kernel<<<3200, 256, 0, stream>>>(input, Xbf);
    pack_wx_kernel<<<3584, 256, 0, stream>>>(Wx, WxP);
    pack_wh_kernel<<<7168, 256, 0, stream>>>(Wh, WhP);

    precompute_kernel<<<dim3(28, 200), 256, 0, stream>>>(Xbf, WxP, bias, Xb);

    recurrent_kernel<<<NBLK, 64, 0, stream>>>(
        Xb, WhP, dur,
        (u64*)h0s, (u64*)h1s,
        flags, out);
}